// Round 2
// 1080.825 us; speedup vs baseline: 1.3653x; 1.3653x over previous
//
#include <hip/hip_runtime.h>
#include <math.h>

#define DD 64
#define HIDN 32
#define NH 3
#define KMAX 4                      // fast-path: up to 4*64 = 256 atoms/segment in regs
#define SMAX_FAST (KMAX * 64)
#define SMAX_LDS 512                // fused-fallback LDS capacity

// ---------------------------------------------------------------------------
// Kernel 1: segment offsets. seg_start[g] = first index i with owner[i] >= g
// (lower_bound). owner is sorted. Handles empty segments via gap fill.
// ---------------------------------------------------------------------------
__global__ void seg_offsets_k(const int* __restrict__ owner, int N, int G,
                              int* __restrict__ seg_start) {
    int i = blockIdx.x * blockDim.x + threadIdx.x;
    if (i >= N) return;
    int cur  = owner[i];
    int prev = (i == 0) ? -1 : owner[i - 1];
    for (int g = prev + 1; g <= cur; ++g) seg_start[g] = i;
    if (i == N - 1) {
        for (int g = cur + 1; g <= G; ++g) seg_start[g] = N;
    }
}

// ---------------------------------------------------------------------------
// Per-atom MLP: scores = silu(x @ w1 + b1) @ w2 + b2   (fp32 throughout)
// hid[32] accumulators = 32 independent FMA chains (issue-bound, not
// latency-bound). w1/w2/b1/b2 addresses are lane-uniform -> scalar loads.
// ---------------------------------------------------------------------------
static __device__ __forceinline__ void mlp_scores(
    const float* __restrict__ fr, const float* __restrict__ w1,
    const float* __restrict__ b1, const float* __restrict__ w2,
    const float* __restrict__ b2, float& s0, float& s1, float& s2) {
    float hid[HIDN];
#pragma unroll
    for (int j = 0; j < HIDN; ++j) hid[j] = b1[j];

    const float4* fr4 = (const float4*)fr;
    for (int q = 0; q < DD / 4; ++q) {          // 16 iterations, 128 FMA each
        float4 f = fr4[q];
        const float* w1r = w1 + (q * 4) * HIDN;
#pragma unroll
        for (int j = 0; j < HIDN; ++j) {
            hid[j] += f.x * w1r[j];
            hid[j] += f.y * w1r[HIDN + j];
            hid[j] += f.z * w1r[2 * HIDN + j];
            hid[j] += f.w * w1r[3 * HIDN + j];
        }
    }
    s0 = b2[0]; s1 = b2[1]; s2 = b2[2];
#pragma unroll
    for (int j = 0; j < HIDN; ++j) {
        float v = hid[j];
        v = v * __builtin_amdgcn_rcpf(1.0f + __expf(-v));   // silu
        s0 += v * w2[j * NH + 0];
        s1 += v * w2[j * NH + 1];
        s2 += v * w2[j * NH + 2];
    }
}

static __device__ __forceinline__ float wave_max(float v) {
#pragma unroll
    for (int m = 32; m >= 1; m >>= 1) v = fmaxf(v, __shfl_xor(v, m, 64));
    return v;
}
static __device__ __forceinline__ float wave_sum(float v) {
#pragma unroll
    for (int m = 32; m >= 1; m >>= 1) v += __shfl_xor(v, m, 64);
    return v;
}

// ---------------------------------------------------------------------------
// Kernel 2 (split path): atom-parallel score MLP. Full occupancy, VALU-bound.
// scores are written padded to float4 ([N][4], w unused) for 16B loads later.
// ---------------------------------------------------------------------------
__global__ void __launch_bounds__(256) scores_k(
    const float* __restrict__ feas, const float* __restrict__ w1,
    const float* __restrict__ b1, const float* __restrict__ w2,
    const float* __restrict__ b2, int N, float4* __restrict__ scores) {
    int i = blockIdx.x * 256 + threadIdx.x;
    if (i >= N) return;
    float s0, s1, s2;
    mlp_scores(feas + (size_t)i * DD, w1, b1, w2, b2, s0, s1, s2);
    scores[i] = make_float4(s0, s1, s2, 0.0f);
}

// ---------------------------------------------------------------------------
// Big-segment pooling fallback (seg > 256): sweeps global scores, no LDS,
// no barriers. Rare/never expected (mean seg = 40).
// ---------------------------------------------------------------------------
static __device__ __attribute__((noinline)) void big_pool(
    const float* __restrict__ feas, const float4* __restrict__ scores,
    int lo, int hi, int lane, float* __restrict__ outg) {
    float m0 = -INFINITY, m1 = -INFINITY, m2 = -INFINITY;
    for (int i = lo + lane; i < hi; i += 64) {
        float4 s = scores[i];
        m0 = fmaxf(m0, s.x); m1 = fmaxf(m1, s.y); m2 = fmaxf(m2, s.z);
    }
    m0 = wave_max(m0); m1 = wave_max(m1); m2 = wave_max(m2);
    float d0 = 0.f, d1 = 0.f, d2 = 0.f;
    for (int i = lo + lane; i < hi; i += 64) {
        float4 s = scores[i];
        d0 += __expf(s.x - m0); d1 += __expf(s.y - m1); d2 += __expf(s.z - m2);
    }
    d0 = wave_sum(d0); d1 = wave_sum(d1); d2 = wave_sum(d2);
    float a0 = 0.f, a1 = 0.f, a2 = 0.f;
    for (int base = lo; base < hi; base += 64) {
        int i = base + lane;
        float e0v = 0.f, e1v = 0.f, e2v = 0.f;
        if (i < hi) {
            float4 s = scores[i];
            e0v = __expf(s.x - m0); e1v = __expf(s.y - m1); e2v = __expf(s.z - m2);
        }
        int cnt = min(64, hi - base);
        for (int j = 0; j < cnt; ++j) {
            float f = feas[(size_t)(base + j) * DD + lane];
            a0 += f * __shfl(e0v, j, 64);
            a1 += f * __shfl(e1v, j, 64);
            a2 += f * __shfl(e2v, j, 64);
        }
    }
    outg[lane * 3 + 0] = a0 * __builtin_amdgcn_rcpf(d0);
    outg[lane * 3 + 1] = a1 * __builtin_amdgcn_rcpf(d1);
    outg[lane * 3 + 2] = a2 * __builtin_amdgcn_rcpf(d2);
}

// ---------------------------------------------------------------------------
// Kernel 3 (split path): segment softmax + weighted pooling.
// 4 waves/block (one segment per wave), ZERO LDS, no barriers: exp-weights
// live in registers (up to 4 chunks of 64 atoms) and broadcast via __shfl.
// Segments walked in REVERSE order so early feas re-reads hit the L3 tail
// that scores_k just streamed.
// ---------------------------------------------------------------------------
__global__ void __launch_bounds__(256) pool_k(
    const float* __restrict__ feas, const float4* __restrict__ scores,
    const int* __restrict__ seg_start, int G, float* __restrict__ out) {
    const int gi = blockIdx.x * 4 + (threadIdx.x >> 6);
    const int lane = threadIdx.x & 63;
    if (gi >= G) return;
    const int g = G - 1 - gi;                 // reverse order: L3 reuse
    const int lo = seg_start[g];
    const int hi = seg_start[g + 1];
    const int seg = hi - lo;
    float* outg = out + (size_t)g * (DD * NH);

    if (seg <= 0) {   // empty segment: reference segment_sum gives zeros
        outg[lane] = 0.f; outg[lane + 64] = 0.f; outg[lane + 128] = 0.f;
        return;
    }
    if (seg > SMAX_FAST) {
        big_pool(feas, scores, lo, hi, lane, outg);
        return;
    }

    // ---- Phase 1: load scores into registers (lane = atom within chunk)
    float e0[KMAX], e1[KMAX], e2[KMAX];
    float m0 = -INFINITY, m1 = -INFINITY, m2 = -INFINITY;
#pragma unroll
    for (int k = 0; k < KMAX; ++k) {
        int i = k * 64 + lane;
        if (i < seg) {
            float4 s = scores[lo + i];
            e0[k] = s.x; e1[k] = s.y; e2[k] = s.z;
        } else {
            e0[k] = -INFINITY; e1[k] = -INFINITY; e2[k] = -INFINITY;
        }
        m0 = fmaxf(m0, e0[k]); m1 = fmaxf(m1, e1[k]); m2 = fmaxf(m2, e2[k]);
    }
    m0 = wave_max(m0); m1 = wave_max(m1); m2 = wave_max(m2);

    // ---- Phase 2: exp + denominators (exp(-inf - m) = 0 pads naturally)
    float d0 = 0.f, d1 = 0.f, d2 = 0.f;
#pragma unroll
    for (int k = 0; k < KMAX; ++k) {
        if (k * 64 < seg) {
            e0[k] = __expf(e0[k] - m0); d0 += e0[k];
            e1[k] = __expf(e1[k] - m1); d1 += e1[k];
            e2[k] = __expf(e2[k] - m2); d2 += e2[k];
        } else {
            e0[k] = 0.f; e1[k] = 0.f; e2[k] = 0.f;
        }
    }
    d0 = wave_sum(d0); d1 = wave_sum(d1); d2 = wave_sum(d2);
    const float rd0 = __builtin_amdgcn_rcpf(d0);
    const float rd1 = __builtin_amdgcn_rcpf(d1);
    const float rd2 = __builtin_amdgcn_rcpf(d2);

    // ---- Phase 3: weighted pooling, lane = feature dim d.
    // Manual x4 unroll: 4 independent 256B coalesced loads in flight/wave.
    float a0 = 0.f, a1 = 0.f, a2 = 0.f;
    const float* fb = feas + (size_t)lo * DD + lane;
#pragma unroll
    for (int k = 0; k < KMAX; ++k) {
        if (k * 64 < seg) {
            const int cnt = min(64, seg - k * 64);
            const float* fkb = fb + (size_t)(k * 64) * DD;
            int j = 0;
            for (; j + 4 <= cnt; j += 4) {
                float fA = fkb[(size_t)(j + 0) * DD];
                float fB = fkb[(size_t)(j + 1) * DD];
                float fC = fkb[(size_t)(j + 2) * DD];
                float fD = fkb[(size_t)(j + 3) * DD];
                a0 += fA * __shfl(e0[k], j + 0, 64);
                a1 += fA * __shfl(e1[k], j + 0, 64);
                a2 += fA * __shfl(e2[k], j + 0, 64);
                a0 += fB * __shfl(e0[k], j + 1, 64);
                a1 += fB * __shfl(e1[k], j + 1, 64);
                a2 += fB * __shfl(e2[k], j + 1, 64);
                a0 += fC * __shfl(e0[k], j + 2, 64);
                a1 += fC * __shfl(e1[k], j + 2, 64);
                a2 += fC * __shfl(e2[k], j + 2, 64);
                a0 += fD * __shfl(e0[k], j + 3, 64);
                a1 += fD * __shfl(e1[k], j + 3, 64);
                a2 += fD * __shfl(e2[k], j + 3, 64);
            }
            for (; j < cnt; ++j) {
                float f = fkb[(size_t)j * DD];
                a0 += f * __shfl(e0[k], j, 64);
                a1 += f * __shfl(e1[k], j, 64);
                a2 += f * __shfl(e2[k], j, 64);
            }
        }
    }
    // out[g, d, h] with head fastest: 12B/lane, contiguous 768B per wave
    outg[lane * 3 + 0] = a0 * rd0;
    outg[lane * 3 + 1] = a1 * rd1;
    outg[lane * 3 + 2] = a2 * rd2;
}

// ---------------------------------------------------------------------------
// Fused fallback (only if workspace can't hold scores): previous-best kernel.
// ---------------------------------------------------------------------------
static __device__ __attribute__((noinline)) void big_segment_path_fused(
    const float* __restrict__ feas, const float* __restrict__ w1,
    const float* __restrict__ b1, const float* __restrict__ w2,
    const float* __restrict__ b2, float* __restrict__ sc,
    int lo, int hi, int lane, float* __restrict__ outg) {
    float m0 = -INFINITY, m1 = -INFINITY, m2 = -INFINITY;
    for (int base = lo; base < hi; base += 64) {
        int a = base + lane;
        if (a < hi) {
            float s0, s1, s2;
            mlp_scores(feas + (size_t)a * DD, w1, b1, w2, b2, s0, s1, s2);
            m0 = fmaxf(m0, s0); m1 = fmaxf(m1, s1); m2 = fmaxf(m2, s2);
        }
    }
    m0 = wave_max(m0); m1 = wave_max(m1); m2 = wave_max(m2);
    float d0 = 0.f, d1 = 0.f, d2 = 0.f;
    for (int base = lo; base < hi; base += 64) {
        int a = base + lane;
        if (a < hi) {
            float s0, s1, s2;
            mlp_scores(feas + (size_t)a * DD, w1, b1, w2, b2, s0, s1, s2);
            d0 += __expf(s0 - m0); d1 += __expf(s1 - m1); d2 += __expf(s2 - m2);
        }
    }
    d0 = wave_sum(d0); d1 = wave_sum(d1); d2 = wave_sum(d2);
    float rd0 = __builtin_amdgcn_rcpf(d0);
    float rd1 = __builtin_amdgcn_rcpf(d1);
    float rd2 = __builtin_amdgcn_rcpf(d2);
    float a0 = 0.f, a1 = 0.f, a2 = 0.f;
    for (int base = lo; base < hi; base += 64) {
        int a = base + lane;
        int cnt = min(64, hi - base);
        __syncthreads();
        if (a < hi) {
            float s0, s1, s2;
            mlp_scores(feas + (size_t)a * DD, w1, b1, w2, b2, s0, s1, s2);
            sc[lane * 3 + 0] = __expf(s0 - m0);
            sc[lane * 3 + 1] = __expf(s1 - m1);
            sc[lane * 3 + 2] = __expf(s2 - m2);
        }
        __syncthreads();
        for (int i = 0; i < cnt; ++i) {
            float f = feas[(size_t)(base + i) * DD + lane];
            a0 += f * sc[i * 3 + 0];
            a1 += f * sc[i * 3 + 1];
            a2 += f * sc[i * 3 + 2];
        }
    }
    outg[lane * 3 + 0] = a0 * rd0;
    outg[lane * 3 + 1] = a1 * rd1;
    outg[lane * 3 + 2] = a2 * rd2;
}

__global__ void __launch_bounds__(64) seg_attn_pool_fused_k(
    const float* __restrict__ feas, const float* __restrict__ w1,
    const float* __restrict__ b1, const float* __restrict__ w2,
    const float* __restrict__ b2, const int* __restrict__ seg_start,
    float* __restrict__ out) {
    __shared__ float sc[SMAX_LDS * 3];
    const int g = blockIdx.x;
    const int lane = threadIdx.x;
    const int lo = seg_start[g];
    const int hi = seg_start[g + 1];
    const int seg = hi - lo;
    float* outg = out + (size_t)g * (DD * NH);

    if (seg <= 0) {
        outg[lane] = 0.f; outg[lane + 64] = 0.f; outg[lane + 128] = 0.f;
        return;
    }
    if (seg > SMAX_LDS) {
        big_segment_path_fused(feas, w1, b1, w2, b2, sc, lo, hi, lane, outg);
        return;
    }
    for (int base = 0; base < seg; base += 64) {
        int i = base + lane;
        if (i < seg) {
            float s0, s1, s2;
            mlp_scores(feas + (size_t)(lo + i) * DD, w1, b1, w2, b2, s0, s1, s2);
            sc[i * 3 + 0] = s0; sc[i * 3 + 1] = s1; sc[i * 3 + 2] = s2;
        }
    }
    __syncthreads();
    float m0 = -INFINITY, m1 = -INFINITY, m2 = -INFINITY;
    for (int i = lane; i < seg; i += 64) {
        m0 = fmaxf(m0, sc[i * 3 + 0]);
        m1 = fmaxf(m1, sc[i * 3 + 1]);
        m2 = fmaxf(m2, sc[i * 3 + 2]);
    }
    m0 = wave_max(m0); m1 = wave_max(m1); m2 = wave_max(m2);
    float d0 = 0.f, d1 = 0.f, d2 = 0.f;
    for (int i = lane; i < seg; i += 64) {
        float e0 = __expf(sc[i * 3 + 0] - m0);
        float e1 = __expf(sc[i * 3 + 1] - m1);
        float e2 = __expf(sc[i * 3 + 2] - m2);
        sc[i * 3 + 0] = e0; sc[i * 3 + 1] = e1; sc[i * 3 + 2] = e2;
        d0 += e0; d1 += e1; d2 += e2;
    }
    __syncthreads();
    d0 = wave_sum(d0); d1 = wave_sum(d1); d2 = wave_sum(d2);
    const float rd0 = __builtin_amdgcn_rcpf(d0);
    const float rd1 = __builtin_amdgcn_rcpf(d1);
    const float rd2 = __builtin_amdgcn_rcpf(d2);
    float a0 = 0.f, a1 = 0.f, a2 = 0.f;
    const float* fbase = feas + (size_t)lo * DD + lane;
    for (int i = 0; i < seg; ++i) {
        float f = fbase[(size_t)i * DD];
        a0 += f * sc[i * 3 + 0];
        a1 += f * sc[i * 3 + 1];
        a2 += f * sc[i * 3 + 2];
    }
    outg[lane * 3 + 0] = a0 * rd0;
    outg[lane * 3 + 1] = a1 * rd1;
    outg[lane * 3 + 2] = a2 * rd2;
}

extern "C" void kernel_launch(void* const* d_in, const int* in_sizes, int n_in,
                              void* d_out, int out_size, void* d_ws, size_t ws_size,
                              hipStream_t stream) {
    const float* feas  = (const float*)d_in[0];
    const float* w1    = (const float*)d_in[1];
    const float* b1    = (const float*)d_in[2];
    const float* w2    = (const float*)d_in[3];
    const float* b2    = (const float*)d_in[4];
    const int*   owner = (const int*)d_in[5];
    const int N = in_sizes[5];
    const int G = out_size / (DD * NH);

    int* seg_start = (int*)d_ws;                         // (G+1) ints
    size_t off = (((size_t)(G + 1) * sizeof(int)) + 255) & ~(size_t)255;
    float4* scores = (float4*)((char*)d_ws + off);       // [N] float4 (padded)
    size_t need = off + (size_t)N * sizeof(float4);
    float* out = (float*)d_out;

    seg_offsets_k<<<(N + 255) / 256, 256, 0, stream>>>(owner, N, G, seg_start);
    if (ws_size >= need) {
        scores_k<<<(N + 255) / 256, 256, 0, stream>>>(feas, w1, b1, w2, b2, N, scores);
        pool_k<<<(G + 3) / 4, 256, 0, stream>>>(feas, scores, seg_start, G, out);
    } else {
        seg_attn_pool_fused_k<<<G, 64, 0, stream>>>(feas, w1, b1, w2, b2, seg_start, out);
    }
}

// Round 3
// 871.908 us; speedup vs baseline: 1.6924x; 1.2396x over previous
//
#include <hip/hip_runtime.h>
#include <math.h>

#define DD 64
#define HIDN 32
#define NH 3
#define KMAX 4                      // fast-path: up to 4*64 = 256 atoms/segment in regs
#define SMAX_FAST (KMAX * 64)
#define SMAX_LDS 512                // fused-fallback LDS capacity

// ---------------------------------------------------------------------------
// Kernel 1: segment offsets. seg_start[g] = first index i with owner[i] >= g
// (lower_bound). owner is sorted. Handles empty segments via gap fill.
// ---------------------------------------------------------------------------
__global__ void seg_offsets_k(const int* __restrict__ owner, int N, int G,
                              int* __restrict__ seg_start) {
    int i = blockIdx.x * blockDim.x + threadIdx.x;
    if (i >= N) return;
    int cur  = owner[i];
    int prev = (i == 0) ? -1 : owner[i - 1];
    for (int g = prev + 1; g <= cur; ++g) seg_start[g] = i;
    if (i == N - 1) {
        for (int g = cur + 1; g <= G; ++g) seg_start[g] = N;
    }
}

// ---------------------------------------------------------------------------
// Per-atom MLP (generic version, used by fallback paths).
// ---------------------------------------------------------------------------
static __device__ __forceinline__ void mlp_scores(
    const float* __restrict__ fr, const float* __restrict__ w1,
    const float* __restrict__ b1, const float* __restrict__ w2,
    const float* __restrict__ b2, float& s0, float& s1, float& s2) {
    float hid[HIDN];
#pragma unroll
    for (int j = 0; j < HIDN; ++j) hid[j] = b1[j];

    const float4* fr4 = (const float4*)fr;
    for (int q = 0; q < DD / 4; ++q) {
        float4 f = fr4[q];
        const float* w1r = w1 + (q * 4) * HIDN;
#pragma unroll
        for (int j = 0; j < HIDN; ++j) {
            hid[j] += f.x * w1r[j];
            hid[j] += f.y * w1r[HIDN + j];
            hid[j] += f.z * w1r[2 * HIDN + j];
            hid[j] += f.w * w1r[3 * HIDN + j];
        }
    }
    s0 = b2[0]; s1 = b2[1]; s2 = b2[2];
#pragma unroll
    for (int j = 0; j < HIDN; ++j) {
        float v = hid[j];
        v = v * __builtin_amdgcn_rcpf(1.0f + __expf(-v));   // silu
        s0 += v * w2[j * NH + 0];
        s1 += v * w2[j * NH + 1];
        s2 += v * w2[j * NH + 2];
    }
}

static __device__ __forceinline__ float wave_max(float v) {
#pragma unroll
    for (int m = 32; m >= 1; m >>= 1) v = fmaxf(v, __shfl_xor(v, m, 64));
    return v;
}
static __device__ __forceinline__ float wave_sum(float v) {
#pragma unroll
    for (int m = 32; m >= 1; m >>= 1) v += __shfl_xor(v, m, 64);
    return v;
}

// ---------------------------------------------------------------------------
// Kernel 2 (split path): atom-parallel score MLP.
// Row loads hoisted into two 8-load bursts: each burst's 8 dwordx4 hit ONE
// 128B cache line per lane back-to-back -> MSHR-merged, one HBM fetch per
// line (kills the 3.2x over-fetch of the interleaved version).
// Math order identical to mlp_scores (q ascending).
// ---------------------------------------------------------------------------
__global__ void __launch_bounds__(256) scores_k(
    const float* __restrict__ feas, const float* __restrict__ w1,
    const float* __restrict__ b1, const float* __restrict__ w2,
    const float* __restrict__ b2, int N, float4* __restrict__ scores) {
    int i = blockIdx.x * 256 + threadIdx.x;
    if (i >= N) return;
    const float4* fr4 = (const float4*)(feas + (size_t)i * DD);

    float hid[HIDN];
#pragma unroll
    for (int j = 0; j < HIDN; ++j) hid[j] = b1[j];

#pragma unroll
    for (int h = 0; h < 2; ++h) {          // two half-row bursts (1 line/lane each)
        float4 r[8];
#pragma unroll
        for (int p = 0; p < 8; ++p) r[p] = fr4[h * 8 + p];
#pragma unroll
        for (int p = 0; p < 8; ++p) {
            const float* w1r = w1 + ((h * 8 + p) * 4) * HIDN;
#pragma unroll
            for (int j = 0; j < HIDN; ++j) {
                hid[j] += r[p].x * w1r[j];
                hid[j] += r[p].y * w1r[HIDN + j];
                hid[j] += r[p].z * w1r[2 * HIDN + j];
                hid[j] += r[p].w * w1r[3 * HIDN + j];
            }
        }
    }

    float s0 = b2[0], s1 = b2[1], s2 = b2[2];
#pragma unroll
    for (int j = 0; j < HIDN; ++j) {
        float v = hid[j];
        v = v * __builtin_amdgcn_rcpf(1.0f + __expf(-v));   // silu
        s0 += v * w2[j * NH + 0];
        s1 += v * w2[j * NH + 1];
        s2 += v * w2[j * NH + 2];
    }
    scores[i] = make_float4(s0, s1, s2, 0.0f);
}

// ---------------------------------------------------------------------------
// Big-segment pooling fallback (seg > 256). Rare/never (mean seg = 40).
// ---------------------------------------------------------------------------
static __device__ __attribute__((noinline)) void big_pool(
    const float* __restrict__ feas, const float4* __restrict__ scores,
    int lo, int hi, int lane, float* __restrict__ outg) {
    float m0 = -INFINITY, m1 = -INFINITY, m2 = -INFINITY;
    for (int i = lo + lane; i < hi; i += 64) {
        float4 s = scores[i];
        m0 = fmaxf(m0, s.x); m1 = fmaxf(m1, s.y); m2 = fmaxf(m2, s.z);
    }
    m0 = wave_max(m0); m1 = wave_max(m1); m2 = wave_max(m2);
    float d0 = 0.f, d1 = 0.f, d2 = 0.f;
    for (int i = lo + lane; i < hi; i += 64) {
        float4 s = scores[i];
        d0 += __expf(s.x - m0); d1 += __expf(s.y - m1); d2 += __expf(s.z - m2);
    }
    d0 = wave_sum(d0); d1 = wave_sum(d1); d2 = wave_sum(d2);
    float a0 = 0.f, a1 = 0.f, a2 = 0.f;
    for (int base = lo; base < hi; base += 64) {
        int i = base + lane;
        float e0v = 0.f, e1v = 0.f, e2v = 0.f;
        if (i < hi) {
            float4 s = scores[i];
            e0v = __expf(s.x - m0); e1v = __expf(s.y - m1); e2v = __expf(s.z - m2);
        }
        int cnt = min(64, hi - base);
        for (int j = 0; j < cnt; ++j) {
            float f = feas[(size_t)(base + j) * DD + lane];
            a0 += f * __shfl(e0v, j, 64);
            a1 += f * __shfl(e1v, j, 64);
            a2 += f * __shfl(e2v, j, 64);
        }
    }
    outg[lane * 3 + 0] = a0 * __builtin_amdgcn_rcpf(d0);
    outg[lane * 3 + 1] = a1 * __builtin_amdgcn_rcpf(d1);
    outg[lane * 3 + 2] = a2 * __builtin_amdgcn_rcpf(d2);
}

static __device__ __forceinline__ float4 xor_reduce_16_32(float4 v) {
#pragma unroll
    for (int m = 16; m <= 32; m <<= 1) {
        v.x += __shfl_xor(v.x, m, 64);
        v.y += __shfl_xor(v.y, m, 64);
        v.z += __shfl_xor(v.z, m, 64);
        v.w += __shfl_xor(v.w, m, 64);
    }
    return v;
}

// ---------------------------------------------------------------------------
// Kernel 3 (split path): segment softmax + weighted pooling.
// 4 waves/block, one segment per wave, ZERO LDS, no barriers.
// Phase 3 restructured: wave covers 4 atoms x 16 dim-quads per instruction
//   lane = (sub = lane>>4 -> atom residue, c = lane&15 -> dims 4c..4c+3)
//   -> each float4 load is 64 lanes x 16B = 1KB fully coalesced,
//   -> 4x in-flight bytes, 1/4 the load instructions vs scalar-dim version.
// Final shfl_xor(16|32) butterfly folds the 4 atom-residue partials.
// ---------------------------------------------------------------------------
__global__ void __launch_bounds__(256) pool_k(
    const float* __restrict__ feas, const float4* __restrict__ scores,
    const int* __restrict__ seg_start, int G, float* __restrict__ out) {
    const int gi = blockIdx.x * 4 + (threadIdx.x >> 6);
    const int lane = threadIdx.x & 63;
    if (gi >= G) return;
    const int g = G - 1 - gi;                 // reverse order: L3 reuse
    const int lo = seg_start[g];
    const int hi = seg_start[g + 1];
    const int seg = hi - lo;
    float* outg = out + (size_t)g * (DD * NH);

    if (seg <= 0) {   // empty segment: reference segment_sum gives zeros
        outg[lane] = 0.f; outg[lane + 64] = 0.f; outg[lane + 128] = 0.f;
        return;
    }
    if (seg > SMAX_FAST) {
        big_pool(feas, scores, lo, hi, lane, outg);
        return;
    }

    // ---- Phase 1: scores -> registers (lane = atom within chunk), 1KB/instr
    float e0[KMAX], e1[KMAX], e2[KMAX];
    float m0 = -INFINITY, m1 = -INFINITY, m2 = -INFINITY;
#pragma unroll
    for (int k = 0; k < KMAX; ++k) {
        int i = k * 64 + lane;
        if (i < seg) {
            float4 s = scores[lo + i];
            e0[k] = s.x; e1[k] = s.y; e2[k] = s.z;
        } else {
            e0[k] = -INFINITY; e1[k] = -INFINITY; e2[k] = -INFINITY;
        }
        m0 = fmaxf(m0, e0[k]); m1 = fmaxf(m1, e1[k]); m2 = fmaxf(m2, e2[k]);
    }
    m0 = wave_max(m0); m1 = wave_max(m1); m2 = wave_max(m2);

    // ---- Phase 2: exp + denominators (exp(-inf - m) = 0 pads naturally)
    float d0 = 0.f, d1 = 0.f, d2 = 0.f;
#pragma unroll
    for (int k = 0; k < KMAX; ++k) {
        if (k * 64 < seg) {
            e0[k] = __expf(e0[k] - m0); d0 += e0[k];
            e1[k] = __expf(e1[k] - m1); d1 += e1[k];
            e2[k] = __expf(e2[k] - m2); d2 += e2[k];
        } else {
            e0[k] = 0.f; e1[k] = 0.f; e2[k] = 0.f;
        }
    }
    d0 = wave_sum(d0); d1 = wave_sum(d1); d2 = wave_sum(d2);
    const float rd0 = __builtin_amdgcn_rcpf(d0);
    const float rd1 = __builtin_amdgcn_rcpf(d1);
    const float rd2 = __builtin_amdgcn_rcpf(d2);

    // ---- Phase 3: 4 atoms x float4-dims per instruction, fully coalesced
    const int sub = lane >> 4;        // atom residue 0..3
    const int c   = lane & 15;        // dim quad: dims 4c..4c+3
    float4 A0 = make_float4(0.f, 0.f, 0.f, 0.f);
    float4 A1 = A0, A2 = A0;
#pragma unroll
    for (int k = 0; k < KMAX; ++k) {
        if (k * 64 < seg) {
            const int cnt = min(64, seg - k * 64);
            const float* base = feas + (size_t)(lo + k * 64) * DD;
            for (int j = 0; j < cnt; j += 4) {
                const int a = j + sub;                  // atom within chunk
                float w0 = __shfl(e0[k], a, 64);        // 0 for padded atoms
                float w1v = __shfl(e1[k], a, 64);
                float w2v = __shfl(e2[k], a, 64);
                float4 f = make_float4(0.f, 0.f, 0.f, 0.f);
                if (a < cnt)
                    f = *(const float4*)(base + (size_t)a * DD + c * 4);
                A0.x += f.x * w0;  A0.y += f.y * w0;  A0.z += f.z * w0;  A0.w += f.w * w0;
                A1.x += f.x * w1v; A1.y += f.y * w1v; A1.z += f.z * w1v; A1.w += f.w * w1v;
                A2.x += f.x * w2v; A2.y += f.y * w2v; A2.z += f.z * w2v; A2.w += f.w * w2v;
            }
        }
    }
    // fold the 4 atom-residue partials (lanes differing in bits 4,5)
    A0 = xor_reduce_16_32(A0);
    A1 = xor_reduce_16_32(A1);
    A2 = xor_reduce_16_32(A2);
    A0.x *= rd0; A0.y *= rd0; A0.z *= rd0; A0.w *= rd0;
    A1.x *= rd1; A1.y *= rd1; A1.z *= rd1; A1.w *= rd1;
    A2.x *= rd2; A2.y *= rd2; A2.z *= rd2; A2.w *= rd2;

    // out[g, d, h] head-fastest: lane c owns 12 consecutive floats at 48c;
    // lanes sub=0..2 each store one float4 -> 768B contiguous per segment.
    float4 w;
    if (sub == 0)      w = make_float4(A0.x, A1.x, A2.x, A0.y);
    else if (sub == 1) w = make_float4(A1.y, A2.y, A0.z, A1.z);
    else               w = make_float4(A2.z, A0.w, A1.w, A2.w);
    if (sub < 3)
        *(float4*)(outg + c * 12 + sub * 4) = w;
}

// ---------------------------------------------------------------------------
// Fused fallback (only if workspace can't hold scores): previous-best kernel.
// ---------------------------------------------------------------------------
static __device__ __attribute__((noinline)) void big_segment_path_fused(
    const float* __restrict__ feas, const float* __restrict__ w1,
    const float* __restrict__ b1, const float* __restrict__ w2,
    const float* __restrict__ b2, float* __restrict__ sc,
    int lo, int hi, int lane, float* __restrict__ outg) {
    float m0 = -INFINITY, m1 = -INFINITY, m2 = -INFINITY;
    for (int base = lo; base < hi; base += 64) {
        int a = base + lane;
        if (a < hi) {
            float s0, s1, s2;
            mlp_scores(feas + (size_t)a * DD, w1, b1, w2, b2, s0, s1, s2);
            m0 = fmaxf(m0, s0); m1 = fmaxf(m1, s1); m2 = fmaxf(m2, s2);
        }
    }
    m0 = wave_max(m0); m1 = wave_max(m1); m2 = wave_max(m2);
    float d0 = 0.f, d1 = 0.f, d2 = 0.f;
    for (int base = lo; base < hi; base += 64) {
        int a = base + lane;
        if (a < hi) {
            float s0, s1, s2;
            mlp_scores(feas + (size_t)a * DD, w1, b1, w2, b2, s0, s1, s2);
            d0 += __expf(s0 - m0); d1 += __expf(s1 - m1); d2 += __expf(s2 - m2);
        }
    }
    d0 = wave_sum(d0); d1 = wave_sum(d1); d2 = wave_sum(d2);
    float rd0 = __builtin_amdgcn_rcpf(d0);
    float rd1 = __builtin_amdgcn_rcpf(d1);
    float rd2 = __builtin_amdgcn_rcpf(d2);
    float a0 = 0.f, a1 = 0.f, a2 = 0.f;
    for (int base = lo; base < hi; base += 64) {
        int a = base + lane;
        int cnt = min(64, hi - base);
        __syncthreads();
        if (a < hi) {
            float s0, s1, s2;
            mlp_scores(feas + (size_t)a * DD, w1, b1, w2, b2, s0, s1, s2);
            sc[lane * 3 + 0] = __expf(s0 - m0);
            sc[lane * 3 + 1] = __expf(s1 - m1);
            sc[lane * 3 + 2] = __expf(s2 - m2);
        }
        __syncthreads();
        for (int i = 0; i < cnt; ++i) {
            float f = feas[(size_t)(base + i) * DD + lane];
            a0 += f * sc[i * 3 + 0];
            a1 += f * sc[i * 3 + 1];
            a2 += f * sc[i * 3 + 2];
        }
    }
    outg[lane * 3 + 0] = a0 * rd0;
    outg[lane * 3 + 1] = a1 * rd1;
    outg[lane * 3 + 2] = a2 * rd2;
}

__global__ void __launch_bounds__(64) seg_attn_pool_fused_k(
    const float* __restrict__ feas, const float* __restrict__ w1,
    const float* __restrict__ b1, const float* __restrict__ w2,
    const float* __restrict__ b2, const int* __restrict__ seg_start,
    float* __restrict__ out) {
    __shared__ float sc[SMAX_LDS * 3];
    const int g = blockIdx.x;
    const int lane = threadIdx.x;
    const int lo = seg_start[g];
    const int hi = seg_start[g + 1];
    const int seg = hi - lo;
    float* outg = out + (size_t)g * (DD * NH);

    if (seg <= 0) {
        outg[lane] = 0.f; outg[lane + 64] = 0.f; outg[lane + 128] = 0.f;
        return;
    }
    if (seg > SMAX_LDS) {
        big_segment_path_fused(feas, w1, b1, w2, b2, sc, lo, hi, lane, outg);
        return;
    }
    for (int base = 0; base < seg; base += 64) {
        int i = base + lane;
        if (i < seg) {
            float s0, s1, s2;
            mlp_scores(feas + (size_t)(lo + i) * DD, w1, b1, w2, b2, s0, s1, s2);
            sc[i * 3 + 0] = s0; sc[i * 3 + 1] = s1; sc[i * 3 + 2] = s2;
        }
    }
    __syncthreads();
    float m0 = -INFINITY, m1 = -INFINITY, m2 = -INFINITY;
    for (int i = lane; i < seg; i += 64) {
        m0 = fmaxf(m0, sc[i * 3 + 0]);
        m1 = fmaxf(m1, sc[i * 3 + 1]);
        m2 = fmaxf(m2, sc[i * 3 + 2]);
    }
    m0 = wave_max(m0); m1 = wave_max(m1); m2 = wave_max(m2);
    float d0 = 0.f, d1 = 0.f, d2 = 0.f;
    for (int i = lane; i < seg; i += 64) {
        float e0 = __expf(sc[i * 3 + 0] - m0);
        float e1 = __expf(sc[i * 3 + 1] - m1);
        float e2 = __expf(sc[i * 3 + 2] - m2);
        sc[i * 3 + 0] = e0; sc[i * 3 + 1] = e1; sc[i * 3 + 2] = e2;
        d0 += e0; d1 += e1; d2 += e2;
    }
    __syncthreads();
    d0 = wave_sum(d0); d1 = wave_sum(d1); d2 = wave_sum(d2);
    const float rd0 = __builtin_amdgcn_rcpf(d0);
    const float rd1 = __builtin_amdgcn_rcpf(d1);
    const float rd2 = __builtin_amdgcn_rcpf(d2);
    float a0 = 0.f, a1 = 0.f, a2 = 0.f;
    const float* fbase = feas + (size_t)lo * DD + lane;
    for (int i = 0; i < seg; ++i) {
        float f = fbase[(size_t)i * DD];
        a0 += f * sc[i * 3 + 0];
        a1 += f * sc[i * 3 + 1];
        a2 += f * sc[i * 3 + 2];
    }
    outg[lane * 3 + 0] = a0 * rd0;
    outg[lane * 3 + 1] = a1 * rd1;
    outg[lane * 3 + 2] = a2 * rd2;
}

extern "C" void kernel_launch(void* const* d_in, const int* in_sizes, int n_in,
                              void* d_out, int out_size, void* d_ws, size_t ws_size,
                              hipStream_t stream) {
    const float* feas  = (const float*)d_in[0];
    const float* w1    = (const float*)d_in[1];
    const float* b1    = (const float*)d_in[2];
    const float* w2    = (const float*)d_in[3];
    const float* b2    = (const float*)d_in[4];
    const int*   owner = (const int*)d_in[5];
    const int N = in_sizes[5];
    const int G = out_size / (DD * NH);

    int* seg_start = (int*)d_ws;                         // (G+1) ints
    size_t off = (((size_t)(G + 1) * sizeof(int)) + 255) & ~(size_t)255;
    float4* scores = (float4*)((char*)d_ws + off);       // [N] float4 (padded)
    size_t need = off + (size_t)N * sizeof(float4);
    float* out = (float*)d_out;

    seg_offsets_k<<<(N + 255) / 256, 256, 0, stream>>>(owner, N, G, seg_start);
    if (ws_size >= need) {
        scores_k<<<(N + 255) / 256, 256, 0, stream>>>(feas, w1, b1, w2, b2, N, scores);
        pool_k<<<(G + 3) / 4, 256, 0, stream>>>(feas, scores, seg_start, G, out);
    } else {
        seg_attn_pool_fused_k<<<G, 64, 0, stream>>>(feas, w1, b1, w2, b2, seg_start, out);
    }
}